// Round 6
// baseline (71.388 us; speedup 1.0000x reference)
//
#include <hip/hip_runtime.h>
#include <math.h>

#define T 2048
#define D 3
#define P 3
#define NK 11              // 2*KMAX+1
#define SUM_K2 110.0f      // 2*(1+4+9+16+25)
#define TWO_PI_F 6.28318530717958647692f
#define INV_TWO_PI_F 0.15915494309189533577f
#define PI_F 3.14159265358979323846f

#define TP (T - 1 - P)     // 2044 outputs per series
#define OUT_PER_THREAD 8   // 256 threads x 8 = 2048 >= TP -> 1 block/series

// Torus logmap: wrap to [-pi, pi]. Reference is floor-mod -> [-pi, pi);
// difference only at exact +/-pi boundary (measure-zero for random floats).
__device__ __forceinline__ float wrap_pi(float x) {
    float k = rintf(x * INV_TWO_PI_F);     // v_rndne_f32
    return fmaf(-k, TWO_PI_F, x);          // x - 2pi*k
}

// Lessons encoded here:
//  - r1: 2048 same-line device atomics serialize at the coherence point (~15us).
//  - r4: per-block __threadfence (L2 writeback on non-coherent per-XCD L2s)
//        costs ~60us. Cross-kernel visibility is free at dispatch boundaries.
//  - r5: barrier-free, LDS-free, straight-from-global structure works.
// This round: 8 outputs/thread -> ONE block per series (512 blocks, 2/CU x 4
// waves). Per thread: 9 aligned float4 loads (rows t..t+11; 1.5x halo, mostly
// L1-absorbed since neighbor threads share lines), 33 in-register wraps, 24 AR
// residuals. Half the blocks/wave-reductions/partials of round 5.
__global__ __launch_bounds__(256) void arp_kernel(
    const float* __restrict__ g,
    const float* __restrict__ ar_phi,   // (D,P)
    const float* __restrict__ ar_eta,   // (D,)
    const float* __restrict__ ar_c,     // (D,)
    float* __restrict__ partial,        // (n_series,) [use_ws]
    float* __restrict__ out,            // (n_mc,)     [!use_ws]
    int n_samples,
    int use_ws)
{
    __shared__ float wave_sums[4];

    const int series = blockIdx.x;
    const int tid    = threadIdx.x;
    const int t      = tid * OUT_PER_THREAD;   // 0..2040, always < TP

    // Per-dim parameters (tiny, L2-broadcast) + analytic winding constant.
    float ph[D][P], inv_s2[D], cc[D];
    float Cd_sum = 0.0f;
    #pragma unroll
    for (int d = 0; d < D; ++d) {
        float s = fabsf(ar_eta[d]);            // scale = sqrt(eta^2)
        inv_s2[d] = 1.0f / (s * s);
        cc[d] = ar_c[d];
        #pragma unroll
        for (int j = 0; j < P; ++j) ph[d][j] = ar_phi[d * P + j];
        // Sum over 11 windings of the non-quadratic parts:
        //   -0.5/s^2 * 4pi^2 * SUM_K2  - NK*log(s) - (NK/2)*log(2pi)
        Cd_sum += -0.5f * inv_s2[d] * (4.0f * PI_F * PI_F * SUM_K2)
                  - (float)NK * logf(s)
                  - 0.5f * (float)NK * logf(TWO_PI_F);
    }

    // Valid outputs for this thread: min(8, TP - t). Only tid==255 is partial
    // (t=2040 -> 4 valid). Its loads are clamped to the series end (rows
    // 2040..2047 = 6 float4 exactly); unrolled loop masks the rest.
    const int nval = min(OUT_PER_THREAD, TP - t);
    const int nvec = min(9, (T * D - t * 3) >> 2);   // 9, or 6 for tid==255

    // 36 floats = g rows t..t+11. Byte offset 96*tid -> 16B-aligned.
    const float4* src4 = (const float4*)(g + (size_t)series * (T * D) + t * 3);
    float4 q[9];
    #pragma unroll
    for (int m = 0; m < 9; ++m)
        q[m] = (m < nvec) ? src4[m] : make_float4(0.f, 0.f, 0.f, 0.f);

    float vv[36];
    #pragma unroll
    for (int m = 0; m < 9; ++m) {
        vv[4 * m + 0] = q[m].x;  vv[4 * m + 1] = q[m].y;
        vv[4 * m + 2] = q[m].z;  vv[4 * m + 3] = q[m].w;
    }

    // Wrapped increments dx[r][d] for r = t..t+10 (11 rows), in registers.
    float dxv[33];
    #pragma unroll
    for (int m = 0; m < 33; ++m) dxv[m] = wrap_pi(vv[m + 3] - vv[m]);

    // 8 outputs: dy[t+k][d] = dx[t+k+3][d] - sum_j ph[d][j]*dx[t+k+2-j][d]
    float q2 = 0.0f;
    #pragma unroll
    for (int k = 0; k < OUT_PER_THREAD; ++k) {
        if (k < nval) {
            #pragma unroll
            for (int d = 0; d < D; ++d) {
                float dy = dxv[(k + 3) * 3 + d]
                         - (ph[d][0] * dxv[(k + 2) * 3 + d]
                          + ph[d][1] * dxv[(k + 1) * 3 + d]
                          + ph[d][2] * dxv[k * 3 + d]);
                float z = dy - cc[d];
                q2 = fmaf(z * z, inv_s2[d], q2);
            }
        }
    }
    float acc = -0.5f * (float)NK * q2;        // -5.5 * sum(z^2/s^2)

    // Wave shuffle reduction, then cross-wave via LDS; one store/block.
    #pragma unroll
    for (int off = 32; off > 0; off >>= 1) acc += __shfl_down(acc, off, 64);
    const int wave = tid >> 6, lane = tid & 63;
    if (lane == 0) wave_sums[wave] = acc;
    __syncthreads();
    if (tid == 0) {
        float block_sum = wave_sums[0] + wave_sums[1] + wave_sums[2] + wave_sums[3];
        block_sum += (float)TP * Cd_sum;       // whole series in this block
        if (use_ws) {
            partial[series] = block_sum;       // disjoint plain store
        } else {
            const int mc = series / n_samples;
            atomicAdd(&out[mc], block_sum);    // fallback (round-0 semantics)
        }
    }
}

// Block mc sums its per_mc contiguous partials and writes out[mc] directly.
// Cross-kernel visibility of `partial` is guaranteed by the dispatch-boundary
// release/acquire (no fences needed — round-4 lesson).
__global__ __launch_bounds__(64) void reduce_kernel(
    const float* __restrict__ partial,
    float* __restrict__ out,
    int per_mc)
{
    const int mc = blockIdx.x;
    float v = 0.0f;
    for (int i = threadIdx.x; i < per_mc; i += 64)
        v += partial[(size_t)mc * per_mc + i];
    #pragma unroll
    for (int off = 32; off > 0; off >>= 1) v += __shfl_down(v, off, 64);
    if (threadIdx.x == 0) out[mc] = v;
}

extern "C" void kernel_launch(void* const* d_in, const int* in_sizes, int n_in,
                              void* d_out, int out_size, void* d_ws, size_t ws_size,
                              hipStream_t stream) {
    const float* g      = (const float*)d_in[0];
    const float* ar_phi = (const float*)d_in[1];
    const float* ar_eta = (const float*)d_in[2];
    const float* ar_c   = (const float*)d_in[3];
    float* out = (float*)d_out;

    const int n_series  = in_sizes[0] / (T * D);   // n_mc * n_samples = 512
    const int n_mc      = out_size;                // 32
    const int n_samples = n_series / n_mc;         // 16
    const int per_mc    = n_samples;               // 16 partials per mc

    const int use_ws = (d_ws != nullptr &&
                        ws_size >= (size_t)n_series * sizeof(float)) ? 1 : 0;
    float* partial = (float*)d_ws;

    if (!use_ws) {
        // d_out is poisoned (0xAA) before every timed launch — zero it.
        hipMemsetAsync(out, 0, (size_t)out_size * sizeof(float), stream);
    }
    arp_kernel<<<n_series, 256, 0, stream>>>(g, ar_phi, ar_eta, ar_c,
                                             partial, out, n_samples, use_ws);
    if (use_ws)
        reduce_kernel<<<n_mc, 64, 0, stream>>>(partial, out, per_mc);
}

// Round 7
// 68.958 us; speedup vs baseline: 1.0352x; 1.0352x over previous
//
#include <hip/hip_runtime.h>
#include <math.h>

#define T 2048
#define D 3
#define P 3
#define NK 11              // 2*KMAX+1
#define SUM_K2 110.0f      // 2*(1+4+9+16+25)
#define TWO_PI_F 6.28318530717958647692f
#define INV_TWO_PI_F 0.15915494309189533577f
#define PI_F 3.14159265358979323846f

#define TP (T - 1 - P)     // 2044 outputs per series
#define OUT_PER_THREAD 4
#define OUT_PER_BLOCK 1024 // 256 threads * 4
#define BLOCKS_PER_SERIES 2

// Torus logmap: wrap to [-pi, pi]. Reference is floor-mod -> [-pi, pi);
// difference only at exact +/-pi boundary (measure-zero for random floats).
__device__ __forceinline__ float wrap_pi(float x) {
    float k = rintf(x * INV_TWO_PI_F);     // v_rndne_f32
    return fmaf(-k, TWO_PI_F, x);          // x - 2pi*k
}

// Session ledger (measured):
//  - r1: 2048 same-line device atomics serialize at coherence point (~15us).
//  - r4: per-block __threadfence (L2 writeback, non-coherent per-XCD L2s)
//        cost ~60us. Cross-kernel visibility is free at dispatch boundaries.
//  - r5: BEST = 68.2us. LDS-free, barrier-free, 4 outputs/thread, 1024 blocks
//        (4/CU x 4 waves), two-dispatch plain-store reduce.
//  - r6: 8 outputs/thread / 512 blocks regressed +3.2us (half the waves ->
//        less latency hiding; +12 live floats/thread; halo saving < 1us).
// This round: exact revert to r5 (best measured).
__global__ __launch_bounds__(256) void arp_kernel(
    const float* __restrict__ g,
    const float* __restrict__ ar_phi,   // (D,P)
    const float* __restrict__ ar_eta,   // (D,)
    const float* __restrict__ ar_c,     // (D,)
    float* __restrict__ partial,        // (n_series*BLOCKS_PER_SERIES,) [use_ws]
    float* __restrict__ out,            // (n_mc,)                       [!use_ws]
    int n_samples,
    int use_ws)
{
    __shared__ float wave_sums[4];

    const int blk    = blockIdx.x;
    const int series = blk >> 1;
    const int half   = blk & 1;
    const int tid    = threadIdx.x;
    const int t      = half * OUT_PER_BLOCK + tid * OUT_PER_THREAD;

    // Per-dim parameters (tiny, L2-broadcast) + analytic winding constant.
    float ph[D][P], inv_s2[D], cc[D];
    float Cd_sum = 0.0f;
    #pragma unroll
    for (int d = 0; d < D; ++d) {
        float s = fabsf(ar_eta[d]);            // scale = sqrt(eta^2)
        inv_s2[d] = 1.0f / (s * s);
        cc[d] = ar_c[d];
        #pragma unroll
        for (int j = 0; j < P; ++j) ph[d][j] = ar_phi[d * P + j];
        // Sum over 11 windings of the non-quadratic parts:
        //   -0.5/s^2 * 4pi^2 * SUM_K2  - NK*log(s) - (NK/2)*log(2pi)
        Cd_sum += -0.5f * inv_s2[d] * (4.0f * PI_F * PI_F * SUM_K2)
                  - (float)NK * logf(s)
                  - 0.5f * (float)NK * logf(TWO_PI_F);
    }

    float acc = 0.0f;
    // TP = 2044 = 4*511 -> threads with t < TP have ALL 4 outputs valid
    // (t <= 2040, t+3 <= 2043) and their loads (rows t..t+7 <= 2047) are
    // in-bounds. Only thread 255 of odd blocks (t = 2044) is fully skipped.
    if (t < TP) {
        // 24 floats = g rows t..t+7. Byte offset 48*(global 4-output index)
        // -> 16B-aligned. 6 independent float4 loads, one latency round.
        const float4* src4 = (const float4*)(g + (size_t)series * (T * D) + t * 3);
        float4 q[6];
        #pragma unroll
        for (int m = 0; m < 6; ++m) q[m] = src4[m];

        float vv[24];
        #pragma unroll
        for (int m = 0; m < 6; ++m) {
            vv[4 * m + 0] = q[m].x;  vv[4 * m + 1] = q[m].y;
            vv[4 * m + 2] = q[m].z;  vv[4 * m + 3] = q[m].w;
        }

        // Wrapped increments dx[r][d] for r = t..t+6 (7 rows), in registers.
        float dxv[21];
        #pragma unroll
        for (int m = 0; m < 21; ++m) dxv[m] = wrap_pi(vv[m + 3] - vv[m]);

        // 4 outputs: dy[t+k][d] = dx[t+k+3][d] - sum_j ph[d][j]*dx[t+k+2-j][d]
        float q2 = 0.0f;
        #pragma unroll
        for (int k = 0; k < 4; ++k) {
            #pragma unroll
            for (int d = 0; d < D; ++d) {
                float dy = dxv[(k + 3) * 3 + d]
                         - (ph[d][0] * dxv[(k + 2) * 3 + d]
                          + ph[d][1] * dxv[(k + 1) * 3 + d]
                          + ph[d][2] * dxv[k * 3 + d]);
                float z = dy - cc[d];
                q2 = fmaf(z * z, inv_s2[d], q2);
            }
        }
        acc = -0.5f * (float)NK * q2;          // -5.5 * sum(z^2/s^2)
    }

    // Wave shuffle reduction, then cross-wave via LDS; one store/block.
    #pragma unroll
    for (int off = 32; off > 0; off >>= 1) acc += __shfl_down(acc, off, 64);
    const int wave = tid >> 6, lane = tid & 63;
    if (lane == 0) wave_sums[wave] = acc;
    __syncthreads();
    if (tid == 0) {
        float block_sum = wave_sums[0] + wave_sums[1] + wave_sums[2] + wave_sums[3];
        int cnt = TP - half * OUT_PER_BLOCK;   // valid outputs in this block
        if (cnt > OUT_PER_BLOCK) cnt = OUT_PER_BLOCK;
        block_sum += (float)cnt * Cd_sum;      // analytic winding constant
        if (use_ws) {
            partial[blk] = block_sum;          // disjoint plain store
        } else {
            const int mc = series / n_samples;
            atomicAdd(&out[mc], block_sum);    // fallback (round-0 semantics)
        }
    }
}

// Block mc sums its per_mc contiguous partials and writes out[mc] directly.
// Cross-kernel visibility of `partial` is guaranteed by the dispatch-boundary
// release/acquire (no fences needed — round-4 lesson).
__global__ __launch_bounds__(64) void reduce_kernel(
    const float* __restrict__ partial,
    float* __restrict__ out,
    int per_mc)
{
    const int mc = blockIdx.x;
    float v = 0.0f;
    for (int i = threadIdx.x; i < per_mc; i += 64)
        v += partial[(size_t)mc * per_mc + i];
    #pragma unroll
    for (int off = 32; off > 0; off >>= 1) v += __shfl_down(v, off, 64);
    if (threadIdx.x == 0) out[mc] = v;
}

extern "C" void kernel_launch(void* const* d_in, const int* in_sizes, int n_in,
                              void* d_out, int out_size, void* d_ws, size_t ws_size,
                              hipStream_t stream) {
    const float* g      = (const float*)d_in[0];
    const float* ar_phi = (const float*)d_in[1];
    const float* ar_eta = (const float*)d_in[2];
    const float* ar_c   = (const float*)d_in[3];
    float* out = (float*)d_out;

    const int n_series  = in_sizes[0] / (T * D);       // n_mc * n_samples = 512
    const int n_mc      = out_size;                    // 32
    const int n_samples = n_series / n_mc;             // 16
    const int n_blocks  = n_series * BLOCKS_PER_SERIES;// 1024
    const int per_mc    = n_samples * BLOCKS_PER_SERIES;// 32 partials per mc

    const int use_ws = (d_ws != nullptr &&
                        ws_size >= (size_t)n_blocks * sizeof(float)) ? 1 : 0;
    float* partial = (float*)d_ws;

    if (!use_ws) {
        // d_out is poisoned (0xAA) before every timed launch — zero it.
        hipMemsetAsync(out, 0, (size_t)out_size * sizeof(float), stream);
    }
    arp_kernel<<<n_blocks, 256, 0, stream>>>(g, ar_phi, ar_eta, ar_c,
                                             partial, out, n_samples, use_ws);
    if (use_ws)
        reduce_kernel<<<n_mc, 64, 0, stream>>>(partial, out, per_mc);
}